// Round 1
// 251.697 us; speedup vs baseline: 1.0816x; 1.0816x over previous
//
#include <hip/hip_runtime.h>
#include <hip/hip_bf16.h>
#include <stdint.h>

typedef _Float16 half8 __attribute__((ext_vector_type(8)));
typedef _Float16 half4 __attribute__((ext_vector_type(4)));
typedef float    f32x4 __attribute__((ext_vector_type(4)));

#define MFMA16(a, b, c) __builtin_amdgcn_mfma_f32_16x16x32_f16(a, b, c, 0, 0, 0)

// ---------------------------------------------------------------------------
// Generic fp32->fp16 transpose: X [R][C] fp32 -> Y [C][R] fp16, z-batched.
// ---------------------------------------------------------------------------
__global__ __launch_bounds__(256) void transpose_to_f16(
    const float* __restrict__ X, _Float16* __restrict__ Y,
    int R, int C, long inBS, long outBS)
{
    __shared__ float t[32][33];
    const int bz = blockIdx.z;
    X += (long)bz * inBS;
    Y += (long)bz * outBS;
    const int c0 = blockIdx.x * 32, r0 = blockIdx.y * 32;
    const int tx = threadIdx.x & 31, ty = threadIdx.x >> 5;
#pragma unroll
    for (int i = 0; i < 4; ++i)
        t[ty + i * 8][tx] = X[(long)(r0 + ty + i * 8) * C + c0 + tx];
    __syncthreads();
#pragma unroll
    for (int i = 0; i < 4; ++i)
        Y[(long)(c0 + ty + i * 8) * R + r0 + tx] = (_Float16)t[tx][ty + i * 8];
}

// ---------------------------------------------------------------------------
// MFMA GEMM v3. C = A(fp32) @ BT(fp16).
// Changes vs v2 (R0 of this session):
//  1. Register-prefetch software pipeline: K-tile t+1's global loads are
//     issued right after the LDS-visibility barrier, so HBM/L2 latency hides
//     under tile t's 32 MFMAs (T14 async-stage split). v2 exposed the full
//     load latency every K-step (MfmaUtil 10.5%, VALUBusy 10.9%).
//  2. Bijective XCD-aware block swizzle (8 XCDs): consecutive logical blocks
//     (sharing the A row-panel) land on the SAME XCD's L2 instead of being
//     round-robined across all 8 (v2: FETCH 133 MB vs 54 MB unique).
// ---------------------------------------------------------------------------
__global__ __launch_bounds__(256, 2) void gemm_f16_v2(
    const float* __restrict__ A0, const float* __restrict__ A1,
    const _Float16* __restrict__ BT,
    const float* __restrict__ bias0, const float* __restrict__ bias1,
    void* __restrict__ Cout,
    int N, int lda, int ldbt, int ldc,
    long aBS, long bBS, long cBS,
    int c_half, int atomic, int nks, int kchunk)
{
    __shared__ __align__(16) _Float16 As[128][72];
    __shared__ __align__(16) _Float16 Bs[128][72];

    // --- XCD-aware bijective swizzle (m204 variant), decode x-fastest ---
    const int gx  = gridDim.x, gy = gridDim.y;
    const int nwg = gx * gy * (int)gridDim.z;
    const int lid = (int)blockIdx.x + gx * ((int)blockIdx.y + gy * (int)blockIdx.z);
    const int q8  = nwg >> 3, r8 = nwg & 7;
    const int xcd = lid & 7, loc = lid >> 3;
    const int sw  = (xcd < r8 ? xcd * (q8 + 1) : r8 * (q8 + 1) + (xcd - r8) * q8) + loc;
    const int nt  = sw % gx;
    const int tm2 = sw / gx;
    const int mt  = tm2 % gy;
    const int bz  = tm2 / gy;

    const int b = bz / nks, ks = bz % nks;
    const int kbeg = ks * kchunk;
    const int kend = kbeg + kchunk;

    const float* A = A1 ? (b ? A1 : A0) : (A0 + (long)b * aBS);
    const _Float16* Bb = BT + (long)b * bBS;

    const int n0 = nt * 128;
    const int m0 = mt * 128;
    const int tid  = threadIdx.x;
    const int wave = tid >> 6, lane = tid & 63;
    const int m16  = lane & 15, quad = lane >> 4;

    // staging roles
    const int acol = (tid & 15) * 4;   // A: k-col within tile (x4 fp32)
    const int arb  = tid >> 4;         // A: row base 0..15 (+p*16)
    const int bj   = tid >> 1;         // B: row (n) 0..127
    const int bcc  = (tid & 1) * 32;   // B: k-col chunk
    int jn = n0 + bj; if (jn > N - 1) jn = N - 1;
    const _Float16* bpB = Bb + (long)jn * ldbt;

    f32x4 acc[2][8];
    {
        f32x4 z = {0.f, 0.f, 0.f, 0.f};
#pragma unroll
        for (int i = 0; i < 2; ++i)
#pragma unroll
            for (int j = 0; j < 8; ++j) acc[i][j] = z;
    }

    // prefetch registers
    float4 av[8];
    half8  bv0, bv1, bv2, bv3;

    auto LOADT = [&](int k0) {
#pragma unroll
        for (int p = 0; p < 8; ++p)
            av[p] = *(const float4*)(A + (long)(m0 + arb + p * 16) * lda + k0 + acol);
        const _Float16* bp = bpB + k0 + bcc;
        bv0 = *(const half8*)(bp);
        bv1 = *(const half8*)(bp + 8);
        bv2 = *(const half8*)(bp + 16);
        bv3 = *(const half8*)(bp + 24);
    };
    auto STORE_LDS = [&]() {
#pragma unroll
        for (int p = 0; p < 8; ++p) {
            half4 hv;
            hv[0] = (_Float16)av[p].x; hv[1] = (_Float16)av[p].y;
            hv[2] = (_Float16)av[p].z; hv[3] = (_Float16)av[p].w;
            *(half4*)&As[arb + p * 16][acol] = hv;
        }
        *(half8*)&Bs[bj][bcc]      = bv0;
        *(half8*)&Bs[bj][bcc + 8]  = bv1;
        *(half8*)&Bs[bj][bcc + 16] = bv2;
        *(half8*)&Bs[bj][bcc + 24] = bv3;
    };

    LOADT(kbeg);
    for (int k0 = kbeg; k0 < kend; k0 += 64) {
        STORE_LDS();
        __syncthreads();                       // tile visible to all waves
        if (k0 + 64 < kend) LOADT(k0 + 64);    // latency hides under MFMAs
#pragma unroll
        for (int kss = 0; kss < 2; ++kss) {
            const int ko = kss * 32 + quad * 8;
            const half8 a0 = *(const half8*)&As[wave * 32 + m16][ko];
            const half8 a1 = *(const half8*)&As[wave * 32 + 16 + m16][ko];
#pragma unroll
            for (int c = 0; c < 8; ++c) {
                const half8 bf = *(const half8*)&Bs[c * 16 + m16][ko];
                acc[0][c] = MFMA16(a0, bf, acc[0][c]);
                acc[1][c] = MFMA16(a1, bf, acc[1][c]);
            }
        }
        __syncthreads();                       // compute done; safe to restage
    }

    const float* bias = b ? bias1 : bias0;
    const int addb = (bias != nullptr) && (kbeg == 0);
#pragma unroll
    for (int hh = 0; hh < 2; ++hh) {
#pragma unroll
        for (int c = 0; c < 8; ++c) {
            const int col = n0 + c * 16 + m16;
            if (col >= N) continue;
            const float bb = addb ? bias[col] : 0.f;
#pragma unroll
            for (int r = 0; r < 4; ++r) {
                const int row = m0 + wave * 32 + hh * 16 + quad * 4 + r;
                const float v = acc[hh][c][r] + bb;
                const long idx = (long)b * cBS + (long)row * ldc + col;
                if (atomic)      atomicAdd(&((float*)Cout)[idx], v);
                else if (c_half) ((_Float16*)Cout)[idx] = (_Float16)v;
                else             ((float*)Cout)[idx] = v;
            }
        }
    }
}

// ---------------------------------------------------------------------------
// Pass 1 v3: per (b,h,s) row stats — LDS-staged (unchanged this round).
// ---------------------------------------------------------------------------
__global__ __launch_bounds__(256, 2) void attn_stats(
    const _Float16* __restrict__ q_all, const _Float16* __restrict__ k_all,
    float* __restrict__ m_out, float* __restrict__ il_out)
{
    const int st = blockIdx.x, h = blockIdx.y, b = blockIdx.z;
    const int tid = threadIdx.x, wave = tid >> 6, lane = tid & 63;
    const int m16 = lane & 15, quad = lane >> 4;
    const int s0 = st * 64;
    const int sw = s0 + wave * 16;

    __shared__ __align__(16) _Float16 qs[64][72];
    __shared__ __align__(16) _Float16 ks[64][72];

    const int srow = tid >> 2;              // 0..63
    const int scol = (tid & 3) * 16;        // halves: 0,16,32,48

    {
        const _Float16* qsrc = q_all + ((long)(b * 1024 + s0 + srow)) * 1024 + h * 64 + scol;
        *(half8*)&qs[srow][scol]     = *(const half8*)(qsrc);
        *(half8*)&qs[srow][scol + 8] = *(const half8*)(qsrc + 8);
    }

    const _Float16* ksrcb = k_all + ((long)(b * 1024 + srow)) * 1024 + h * 64 + scol;

    float mr[4], lr[4];
#pragma unroll
    for (int r = 0; r < 4; ++r) { mr[r] = -3.0e38f; lr[r] = 0.f; }

    half8 a0, a1;
    for (int tt = 0; tt <= st; ++tt) {
        const _Float16* ksrc = ksrcb + (long)(tt * 64) * 1024;
        const half8 k0 = *(const half8*)(ksrc);
        const half8 k1 = *(const half8*)(ksrc + 8);

        __syncthreads();
        *(half8*)&ks[srow][scol]     = k0;
        *(half8*)&ks[srow][scol + 8] = k1;
        __syncthreads();

        if (tt == 0) {
            a0 = *(const half8*)&qs[wave * 16 + m16][quad * 8];
            a1 = *(const half8*)&qs[wave * 16 + m16][quad * 8 + 32];
        }

        if (tt < st) {
#pragma unroll
            for (int c = 0; c < 4; ++c) {
                const half8 b0 = *(const half8*)&ks[c * 16 + m16][quad * 8];
                const half8 b1 = *(const half8*)&ks[c * 16 + m16][quad * 8 + 32];
                f32x4 cc = {0.f, 0.f, 0.f, 0.f};
                cc = MFMA16(a0, b0, cc);
                cc = MFMA16(a1, b1, cc);
#pragma unroll
                for (int r = 0; r < 4; ++r) {
                    const float z  = cc[r] * 0.125f;
                    const float nm = fmaxf(mr[r], z);
                    lr[r] = lr[r] * __expf(mr[r] - nm) + __expf(z - nm);
                    mr[r] = nm;
                }
            }
        } else {
#pragma unroll
            for (int c = 0; c < 4; ++c) {
                const half8 b0 = *(const half8*)&ks[c * 16 + m16][quad * 8];
                const half8 b1 = *(const half8*)&ks[c * 16 + m16][quad * 8 + 32];
                f32x4 cc = {0.f, 0.f, 0.f, 0.f};
                cc = MFMA16(a0, b0, cc);
                cc = MFMA16(a1, b1, cc);
                const int col = tt * 64 + c * 16 + m16;
#pragma unroll
                for (int r = 0; r < 4; ++r) {
                    const int row = sw + quad * 4 + r;
                    if (col <= row) {
                        const float z  = cc[r] * 0.125f;
                        const float nm = fmaxf(mr[r], z);
                        lr[r] = lr[r] * __expf(mr[r] - nm) + __expf(z - nm);
                        mr[r] = nm;
                    }
                }
            }
        }
    }

#pragma unroll
    for (int mk = 1; mk < 16; mk <<= 1) {
#pragma unroll
        for (int r = 0; r < 4; ++r) {
            const float om = __shfl_xor(mr[r], mk);
            const float ol = __shfl_xor(lr[r], mk);
            const float nm = fmaxf(mr[r], om);
            lr[r] = lr[r] * __expf(mr[r] - nm) + ol * __expf(om - nm);
            mr[r] = nm;
        }
    }
    if (m16 == 0) {
#pragma unroll
        for (int r = 0; r < 4; ++r) {
            const long idx = ((long)(b * 16 + h)) * 1024 + sw + quad * 4 + r;
            m_out[idx]  = mr[r];
            il_out[idx] = 1.f / lr[r];
        }
    }
}

// ---------------------------------------------------------------------------
// Pass 2 v4: attn_mean = (1/H) sum_h softmax — LDS-staged (unchanged).
// ---------------------------------------------------------------------------
__global__ __launch_bounds__(256, 2) void attn_pmean(
    const _Float16* __restrict__ q_all, const _Float16* __restrict__ k_all,
    const float* __restrict__ m_in, const float* __restrict__ il_in,
    float* __restrict__ attn)
{
    const int ttile = blockIdx.x, stile = blockIdx.y, b = blockIdx.z;
    const int tid = threadIdx.x;
    if (ttile > stile) {
        const int c4 = (tid & 15) * 4;
        float4 z = {0.f, 0.f, 0.f, 0.f};
#pragma unroll
        for (int i = 0; i < 4; ++i) {
            const int r = stile * 64 + (tid >> 4) + i * 16;
            *(float4*)&attn[((long)(b * 1024 + r)) * 1024 + ttile * 64 + c4] = z;
        }
        return;
    }

    __shared__ __align__(16) _Float16 qs[64][72];
    __shared__ __align__(16) _Float16 ks[64][72];

    const int wave = tid >> 6, lane = tid & 63;
    const int m16 = lane & 15, quad = lane >> 4;
    const int s0 = stile * 64;
    const int t0 = ttile * 64;
    const int sw = s0 + wave * 16;
    const int diag = (ttile == stile);

    const int srow = tid >> 2;
    const int scol = (tid & 3) * 16;

    const _Float16* qsrc = q_all + ((long)(b * 1024 + s0 + srow)) * 1024 + scol;
    const _Float16* ksrc = k_all + ((long)(b * 1024 + t0 + srow)) * 1024 + scol;
    const long sbase = ((long)(b * 16)) * 1024 + sw + quad * 4;

    float pm[4][4];
#pragma unroll
    for (int c = 0; c < 4; ++c)
#pragma unroll
        for (int r = 0; r < 4; ++r) pm[c][r] = 0.f;

    for (int h = 0; h < 16; ++h) {
        const int ho = h * 64;
        const half8 q0 = *(const half8*)(qsrc + ho);
        const half8 q1 = *(const half8*)(qsrc + ho + 8);
        const half8 k0 = *(const half8*)(ksrc + ho);
        const half8 k1 = *(const half8*)(ksrc + ho + 8);
        const long idx = sbase + (long)h * 1024;
        const float4 mv = *(const float4*)&m_in[idx];
        const float4 iv = *(const float4*)&il_in[idx];

        __syncthreads();
        *(half8*)&qs[srow][scol]     = q0;
        *(half8*)&qs[srow][scol + 8] = q1;
        *(half8*)&ks[srow][scol]     = k0;
        *(half8*)&ks[srow][scol + 8] = k1;
        __syncthreads();

        const half8 a0 = *(const half8*)&qs[wave * 16 + m16][quad * 8];
        const half8 a1 = *(const half8*)&qs[wave * 16 + m16][quad * 8 + 32];
        const float mrow[4] = {mv.x, mv.y, mv.z, mv.w};
        const float irow[4] = {iv.x, iv.y, iv.z, iv.w};

        if (!diag) {
#pragma unroll
            for (int c = 0; c < 4; ++c) {
                const half8 b0 = *(const half8*)&ks[c * 16 + m16][quad * 8];
                const half8 b1 = *(const half8*)&ks[c * 16 + m16][quad * 8 + 32];
                f32x4 cc = {0.f, 0.f, 0.f, 0.f};
                cc = MFMA16(a0, b0, cc);
                cc = MFMA16(a1, b1, cc);
#pragma unroll
                for (int r = 0; r < 4; ++r)
                    pm[c][r] += __expf(cc[r] * 0.125f - mrow[r]) * irow[r];
            }
        } else {
#pragma unroll
            for (int c = 0; c < 4; ++c) {
                const half8 b0 = *(const half8*)&ks[c * 16 + m16][quad * 8];
                const half8 b1 = *(const half8*)&ks[c * 16 + m16][quad * 8 + 32];
                f32x4 cc = {0.f, 0.f, 0.f, 0.f};
                cc = MFMA16(a0, b0, cc);
                cc = MFMA16(a1, b1, cc);
                const int col = t0 + c * 16 + m16;
#pragma unroll
                for (int r = 0; r < 4; ++r) {
                    const int row = sw + quad * 4 + r;
                    if (col <= row)
                        pm[c][r] += __expf(cc[r] * 0.125f - mrow[r]) * irow[r];
                }
            }
        }
    }

#pragma unroll
    for (int c = 0; c < 4; ++c) {
#pragma unroll
        for (int r = 0; r < 4; ++r) {
            const int row = sw + quad * 4 + r;
            const int col = t0 + c * 16 + m16;
            attn[((long)(b * 1024 + row)) * 1024 + col] = pm[c][r] * 0.0625f;
        }
    }
}

// ---------------------------------------------------------------------------
extern "C" void kernel_launch(void* const* d_in, const int* in_sizes, int n_in,
                              void* d_out, int out_size, void* d_ws, size_t ws_size,
                              hipStream_t stream)
{
    const float* queries = (const float*)d_in[0];
    const float* keys    = (const float*)d_in[1];
    const float* values  = (const float*)d_in[2];
    const float* Wq = (const float*)d_in[4];
    const float* bq = (const float*)d_in[5];
    const float* Wk = (const float*)d_in[6];
    const float* bk = (const float*)d_in[7];
    const float* Wv = (const float*)d_in[8];
    const float* bv = (const float*)d_in[9];
    const float* Wo = (const float*)d_in[10];
    const float* bo = (const float*)d_in[11];

    float* out_ptr  = (float*)d_out;                   // [4096][1024]
    float* attn_ptr = out_ptr + (long)4096 * 1024;     // [4][1024][1024]

    uint8_t* w = (uint8_t*)d_ws;
    size_t off = 0;
    auto alloc = [&](size_t bytes) {
        void* p = w + off;
        off = (off + bytes + 255) & ~(size_t)255;
        return p;
    };
    _Float16* WqkT  = (_Float16*)alloc((size_t)2 * 1024 * 1024 * 2); // WqT|WkT [n][d]
    _Float16* WvT   = (_Float16*)alloc((size_t)64 * 1024 * 2);       // [e][d]
    _Float16* WoT   = (_Float16*)alloc((size_t)1024 * 64 * 2);       // [d][e]
    _Float16* qkall = (_Float16*)alloc((size_t)2 * 4194304 * 2);     // qall|kall
    float*    vbuf  = (float*)alloc((size_t)4096 * 64 * 4);
    _Float16* vT    = (_Float16*)alloc((size_t)4 * 64 * 1024 * 2);   // per-b [e][t]
    float*    ctx   = (float*)alloc((size_t)4096 * 64 * 4);
    float*    mbuf  = (float*)alloc((size_t)65536 * 4);
    float*    ilbuf = (float*)alloc((size_t)65536 * 4);
    (void)ws_size; (void)in_sizes; (void)n_in; (void)out_size;

    _Float16* qall = qkall;
    _Float16* kall = qkall + (long)4194304;

    // weight transposes/conversions
    transpose_to_f16<<<dim3(2, 32, 16), 256, 0, stream>>>(Wq, WqkT, 1024, 64, 65536, 65536);
    transpose_to_f16<<<dim3(2, 32, 16), 256, 0, stream>>>(Wk, WqkT + (long)1024 * 1024, 1024, 64, 65536, 65536);
    transpose_to_f16<<<dim3(2, 32, 1),  256, 0, stream>>>(Wv, WvT, 1024, 64, 0, 0);
    transpose_to_f16<<<dim3(32, 2, 1),  256, 0, stream>>>(Wo, WoT, 64, 1024, 0, 0);

    // fused q+k projection: z selects queries/Wq/bq vs keys/Wk/bk; 512 blocks
    gemm_f16_v2<<<dim3(8, 32, 2), 256, 0, stream>>>(
        queries, keys, WqkT, bq, bk, qkall,
        1024, 1024, 1024, 1024,
        0, (long)1048576, (long)4194304,
        /*c_half=*/1, /*atomic=*/0, /*nks=*/1, /*kchunk=*/1024);

    // v projection: split-K x8 atomic into vbuf (zeroed) -> 256 blocks
    hipMemsetAsync(vbuf, 0, (size_t)4096 * 64 * 4, stream);
    gemm_f16_v2<<<dim3(1, 32, 8), 256, 0, stream>>>(
        values, nullptr, WvT, bv, nullptr, vbuf,
        64, 1024, 1024, 64,
        0, 0, 0,
        /*c_half=*/0, /*atomic=*/1, /*nks=*/8, /*kchunk=*/128);

    // vT per batch: [1024][64] -> [64][1024] fp16
    transpose_to_f16<<<dim3(2, 32, 4), 256, 0, stream>>>(vbuf, vT, 1024, 64, 65536, 65536);

    // softmax stats then LDS-staged head-averaged probabilities
    attn_stats<<<dim3(16, 16, 4), 256, 0, stream>>>(qall, kall, mbuf, ilbuf);
    attn_pmean<<<dim3(16, 16, 4), 256, 0, stream>>>(qall, kall, mbuf, ilbuf, attn_ptr);

    // ctx[b] = attn_mean[b] @ v[b]: batch x split-K x8 atomic -> 256 blocks
    hipMemsetAsync(ctx, 0, (size_t)4096 * 64 * 4, stream);
    gemm_f16_v2<<<dim3(1, 8, 32), 256, 0, stream>>>(
        attn_ptr, nullptr, vT, nullptr, nullptr, ctx,
        64, 1024, 1024, 64,
        (long)1048576, (long)65536, (long)65536,
        /*c_half=*/0, /*atomic=*/1, /*nks=*/8, /*kchunk=*/128);

    // out = ctx @ Wo + bo (K=64: single iteration)
    gemm_f16_v2<<<dim3(8, 32, 1), 256, 0, stream>>>(
        ctx, nullptr, WoT, bo, nullptr, out_ptr,
        1024, 64, 64, 1024,
        0, 0, 0,
        /*c_half=*/0, /*atomic=*/0, /*nks=*/1, /*kchunk=*/64);
}